// Round 9
// baseline (283.792 us; speedup 1.0000x reference)
//
#include <hip/hip_runtime.h>

typedef unsigned short u16;
typedef unsigned int u32;
typedef __attribute__((ext_vector_type(8))) __bf16 bf16x8;
typedef __attribute__((ext_vector_type(4))) float f32x4;

// ---- workspace layout (float offsets) ----
constexpr size_t OFF_PI  = 0;                    // pi fp32 [m][64]
constexpr size_t OFF_PBH = 512;                  // P hi bf16 [e][m][c][d] (u16)
constexpr size_t OFF_PBL = OFF_PBH + 1015808;    // P lo

union FR { uint4 u; bf16x8 v; };

// split x -> hi (RNE bf16) + lo (trunc bf16 of residual)
__device__ __forceinline__ void split_bf16(float x, u16& h, u16& l) {
  u32 b = __float_as_uint(x);
  u32 hb = (b + 0x7fffu + ((b >> 16) & 1u)) & 0xffff0000u;
  h = (u16)(hb >> 16);
  float r = x - __uint_as_float(hb);
  l = (u16)(__float_as_uint(r) >> 16);
}

__device__ __forceinline__ void split8(const f32x4 a, const f32x4 b,
                                       uint4& hi, uint4& lo) {
  u16 h[8], l[8];
  split_bf16(a.x, h[0], l[0]); split_bf16(a.y, h[1], l[1]);
  split_bf16(a.z, h[2], l[2]); split_bf16(a.w, h[3], l[3]);
  split_bf16(b.x, h[4], l[4]); split_bf16(b.y, h[5], l[5]);
  split_bf16(b.z, h[6], l[6]); split_bf16(b.w, h[7], l[7]);
  hi.x = h[0] | ((u32)h[1] << 16); hi.y = h[2] | ((u32)h[3] << 16);
  hi.z = h[4] | ((u32)h[5] << 16); hi.w = h[6] | ((u32)h[7] << 16);
  lo.x = l[0] | ((u32)l[1] << 16); lo.y = l[2] | ((u32)l[3] << 16);
  lo.z = l[4] | ((u32)l[5] << 16); lo.w = l[6] | ((u32)l[7] << 16);
}

__device__ __forceinline__ void mfma3(f32x4& a, const uint4 ah, const uint4 al,
                                      const uint4 bh, const uint4 bl) {
  FR Ah, Al, Bh, Bl;
  Ah.u = ah; Al.u = al; Bh.u = bh; Bl.u = bl;
  a = __builtin_amdgcn_mfma_f32_16x16x32_bf16(Ah.v, Bh.v, a, 0, 0, 0);
  a = __builtin_amdgcn_mfma_f32_16x16x32_bf16(Ah.v, Bl.v, a, 0, 0, 0);
  a = __builtin_amdgcn_mfma_f32_16x16x32_bf16(Al.v, Bh.v, a, 0, 0, 0);
}

// bf16 hi/lo matrix buffer: 64 rows x 32 dwords hi + 2048 dwords lo; 16B chunk
// j of row r at ((j+r)&7) -> conflict-free b128.  (k_pcomb only)
__device__ __forceinline__ void xt_read2(const u32* b, int row, int chunk,
                                         uint4& hi, uint4& lo) {
  const int dw = (row << 5) + (((chunk + row) & 7) << 2);
  hi = *(const uint4*)&b[dw];
  lo = *(const uint4*)&b[2048 + dw];
}
__device__ __forceinline__ void xt_write4(u32* b, int row, int cp, int half,
                                          const f32x4 v) {
  u16 h[4], l[4];
  split_bf16(v.x, h[0], l[0]); split_bf16(v.y, h[1], l[1]);
  split_bf16(v.z, h[2], l[2]); split_bf16(v.w, h[3], l[3]);
  const int dw = (row << 5) + (((cp + row) & 7) << 2) + half * 2;
  uint2 hh, ll;
  hh.x = h[0] | ((u32)h[1] << 16); hh.y = h[2] | ((u32)h[3] << 16);
  ll.x = l[0] | ((u32)l[1] << 16); ll.y = l[2] | ((u32)l[3] << 16);
  *(uint2*)&b[dw] = hh;
  *(uint2*)&b[2048 + dw] = ll;
}

// ---------------- K1: pi, Q, DEPTH-4 parallel ladder, combine -> P hi/lo ----
// (R7 proven, unchanged.) 256 blocks x 512 threads; m = blk&7, prt = blk>>3.
__global__ __launch_bounds__(512, 2) void k_pcomb(
    const float* __restrict__ R_inv, const float* __restrict__ pi_inv,
    const float* __restrict__ lengths, float* __restrict__ ws,
    u16* __restrict__ PBH, u16* __restrict__ PBL) {
  const int m = blockIdx.x & 7, prt = blockIdx.x >> 3;
  const int tid = threadIdx.x, lane = tid & 63, w = tid >> 6;  // 8 waves
  const int ln = lane & 15, kq = lane >> 4;
  __shared__ float pis[64];
  __shared__ float n2s;
  __shared__ __align__(16) float Qs[64 * 68];
  __shared__ __align__(16) u32 PB[8][4096];  // row Q1,Q2,Q4,Q8; col Q1,Q2,Q3,Q4

  if (tid < 64) {
    float p = (tid < 63) ? pi_inv[m * 63 + tid] : 0.f;
    float v = p * p;
    #pragma unroll
    for (int off = 32; off; off >>= 1) v += __shfl_down(v, off, 64);
    if (tid == 0) n2s = v;
  }
  __syncthreads();
  if (tid < 64) {
    const float den = n2s + 1.f;
    const float x = (tid < 63) ? 2.f * pi_inv[m * 63 + tid] / den
                               : (n2s - 1.f) / den;
    const float pv = x * x;
    pis[tid] = pv;
    if (prt == 0) ws[OFF_PI + (size_t)m * 64 + tid] = pv;
  }
  __syncthreads();
  for (int idx = tid; idx < 4096; idx += 512) {
    const int i = idx >> 6, j = idx & 63;
    float q = 0.f;
    if (i != j) {
      const int a = min(i, j), b = max(i, j);
      const int kk = a * (127 - a) / 2 + (b - a - 1);
      q = expf(R_inv[m * 2016 + kk]) * pis[j];
    }
    Qs[i * 68 + j] = q;
  }
  __syncthreads();
  if (tid < 64) {
    float s = 0.f;
    #pragma unroll 4
    for (int j4 = 0; j4 < 64; j4 += 4) {
      const f32x4 q = *(const f32x4*)&Qs[tid * 68 + j4];
      s += q.x + q.y + q.z + q.w;
    }
    Qs[tid * 68 + tid] = -s;
  }
  __syncthreads();

  float q[12][2][4];
  #pragma unroll
  for (int tt = 0; tt < 2; ++tt) {
    const int T = w + tt * 8, ct = T >> 2, bt = T & 3;
    #pragma unroll
    for (int r = 0; r < 4; ++r)
      q[0][tt][r] = Qs[(ct * 16 + kq * 4 + r) * 68 + bt * 16 + ln];
  }
  {
    const int i = tid >> 3, c = tid & 7;
    const f32x4 a = *(const f32x4*)&Qs[i * 68 + c * 8];
    const f32x4 b = *(const f32x4*)&Qs[i * 68 + c * 8 + 4];
    uint4 h, l;
    split8(a, b, h, l);
    const int dw = (i << 5) + (((c + i) & 7) << 2);
    *(uint4*)&PB[0][dw] = h;
    *(uint4*)&PB[0][2048 + dw] = l;
    const int j = i;
    f32x4 ca, cb;
    ca.x = Qs[(c * 8 + 0) * 68 + j]; ca.y = Qs[(c * 8 + 1) * 68 + j];
    ca.z = Qs[(c * 8 + 2) * 68 + j]; ca.w = Qs[(c * 8 + 3) * 68 + j];
    cb.x = Qs[(c * 8 + 4) * 68 + j]; cb.y = Qs[(c * 8 + 5) * 68 + j];
    cb.z = Qs[(c * 8 + 6) * 68 + j]; cb.w = Qs[(c * 8 + 7) * 68 + j];
    split8(ca, cb, h, l);
    *(uint4*)&PB[4][dw] = h;
    *(uint4*)&PB[4][2048 + dw] = l;
  }
  __syncthreads();

  const f32x4 z = {0.f, 0.f, 0.f, 0.f};
  auto tileP = [&](const u32* RX, const u32* CY, int T) -> f32x4 {
    const int ct = T >> 2, bt = T & 3;
    uint4 ah[2], al[2], bh[2], bl[2];
    #pragma unroll
    for (int kh = 0; kh < 2; ++kh) {
      xt_read2(RX, ct * 16 + ln, kh * 4 + kq, ah[kh], al[kh]);
      xt_read2(CY, bt * 16 + ln, kh * 4 + kq, bh[kh], bl[kh]);
    }
    f32x4 a = z;
    #pragma unroll
    for (int kh = 0; kh < 2; ++kh) mfma3(a, ah[kh], al[kh], bh[kh], bl[kh]);
    return a;
  };
  auto tileT = [&](const u32* RX, const u32* CY, int T) -> f32x4 {
    const int ct = T >> 2, bt = T & 3;
    uint4 ah[2], al[2], bh[2], bl[2];
    #pragma unroll
    for (int kh = 0; kh < 2; ++kh) {
      xt_read2(CY, ct * 16 + ln, kh * 4 + kq, ah[kh], al[kh]);
      xt_read2(RX, bt * 16 + ln, kh * 4 + kq, bh[kh], bl[kh]);
    }
    f32x4 a = z;
    #pragma unroll
    for (int kh = 0; kh < 2; ++kh) mfma3(a, ah[kh], al[kh], bh[kh], bl[kh]);
    return a;
  };
  auto wbuf = [&](u32* dst, int T, const f32x4 a) {
    const int ct = T >> 2, bt = T & 3;
    xt_write4(dst, bt * 16 + ln, 2 * ct + (kq >> 1), kq & 1, a);
  };

  #pragma unroll
  for (int tt = 0; tt < 2; ++tt) {
    const int T = w + tt * 8;
    const f32x4 a = tileP(PB[0], PB[4], T);
    #pragma unroll
    for (int r = 0; r < 4; ++r) q[1][tt][r] = a[r];
    wbuf(PB[5], T, a);
    wbuf(PB[1], T, tileT(PB[0], PB[4], T));
  }
  __syncthreads();
  #pragma unroll
  for (int tt = 0; tt < 2; ++tt) {
    const int T = w + tt * 8;
    const f32x4 a3 = tileP(PB[1], PB[4], T);
    const f32x4 a4 = tileP(PB[1], PB[5], T);
    #pragma unroll
    for (int r = 0; r < 4; ++r) { q[2][tt][r] = a3[r]; q[3][tt][r] = a4[r]; }
    wbuf(PB[6], T, a3);
    wbuf(PB[7], T, a4);
    wbuf(PB[2], T, tileT(PB[1], PB[5], T));
  }
  __syncthreads();
  #pragma unroll
  for (int tt = 0; tt < 2; ++tt) {
    const int T = w + tt * 8;
    const f32x4 a5 = tileP(PB[2], PB[4], T);
    const f32x4 a6 = tileP(PB[2], PB[5], T);
    const f32x4 a7 = tileP(PB[2], PB[6], T);
    const f32x4 a8 = tileP(PB[2], PB[7], T);
    #pragma unroll
    for (int r = 0; r < 4; ++r) {
      q[4][tt][r] = a5[r]; q[5][tt][r] = a6[r];
      q[6][tt][r] = a7[r]; q[7][tt][r] = a8[r];
    }
    wbuf(PB[3], T, tileT(PB[2], PB[7], T));
  }
  __syncthreads();
  #pragma unroll
  for (int tt = 0; tt < 2; ++tt) {
    const int T = w + tt * 8;
    const f32x4 a9  = tileP(PB[3], PB[4], T);
    const f32x4 a10 = tileP(PB[3], PB[5], T);
    const f32x4 a11 = tileP(PB[3], PB[6], T);
    const f32x4 a12 = tileP(PB[3], PB[7], T);
    #pragma unroll
    for (int r = 0; r < 4; ++r) {
      q[8][tt][r] = a9[r];  q[9][tt][r] = a10[r];
      q[10][tt][r] = a11[r]; q[11][tt][r] = a12[r];
    }
  }

  #pragma unroll
  for (int ei = 0; ei < 2; ++ei) {
    const int e = prt * 2 + ei;
    if (e >= 62) break;
    const float t = lengths[e];
    const size_t base = ((size_t)e * 8 + m) << 12;
    #pragma unroll
    for (int tt = 0; tt < 2; ++tt) {
      const int T = w + tt * 8, ct = T >> 2, bt = T & 3;
      float av[4];
      #pragma unroll
      for (int r = 0; r < 4; ++r)
        av[r] = (ct == bt && ln == kq * 4 + r) ? 1.f : 0.f;
      float cf = 1.f;
      #pragma unroll
      for (int k = 1; k <= 12; ++k) {
        cf *= t / (float)k;
        #pragma unroll
        for (int r = 0; r < 4; ++r) av[r] = fmaf(cf, q[k - 1][tt][r], av[r]);
      }
      #pragma unroll
      for (int r = 0; r < 4; ++r) {
        u16 h, l;
        split_bf16(av[r], h, l);
        const size_t off =
            base + (size_t)(ct * 16 + kq * 4 + r) * 64 + bt * 16 + ln;
        PBH[off] = h;
        PBL[off] = l;
      }
    }
  }
}

// ---------------- K2: depth-first register-resident tree ----------------
// 512 blocks x 64 threads: one WAVE per (m = blk&7 [XCD], 16-col slice).
// No LDS, no barriers. Post-order traversal fully inlined via template
// recursion; node values (16 cols x 64 states, bf16 hi/lo) live in 16 VGPRs;
// max 4 live on the stack. C-layout -> B-fragment conversion is an in-register
// 4-lane shuffle transpose (verified: consumer (ln,kq) takes producer lane
// A = ln+32*(kq&1) / B = A+16's uint2 of ct = kh*2+(kq>>1)).
// Per-node math is bit-identical to the LDS-slot version (same mfma3 order,
// same split/pack); 1 wave/SIMD with up to ~512 VGPR lets the compiler hold
// deep P-load queues and prefetch the next merge's P during current MFMAs.
struct NV { uint2 H[4]; uint2 L[4]; };  // per-lane node value (C layout)

struct Ctx {
  const float* leaves;
  const u16* Phi;
  const u16* Plo;
  int ln, kq, m;
  size_t colbase;  // global batch col of ln==0
};

__device__ __forceinline__ void leafB(const Ctx& c, int leaf, uint4 bh[2],
                                      uint4 bl[2]) {
  #pragma unroll
  for (int kh = 0; kh < 2; ++kh) {
    const float* g = c.leaves + (c.colbase + c.ln) * 2048 +
                     (size_t)leaf * 64 + kh * 32 + c.kq * 8;
    const f32x4 xa = *(const f32x4*)g;
    const f32x4 xb = *(const f32x4*)(g + 4);
    split8(xa, xb, bh[kh], bl[kh]);
  }
}

// NV (C layout) -> B fragments. Two shfl rounds (ct = kh*2 and kh*2+1),
// select by consumer's kq&2.
__device__ __forceinline__ void nvB(const Ctx& c, const NV& v, uint4 bh[2],
                                    uint4 bl[2]) {
  const int A = c.ln + ((c.kq & 1) << 5);
  const int B = A + 16;
  const bool hiCt = (c.kq & 2) != 0;
  #pragma unroll
  for (int kh = 0; kh < 2; ++kh) {
    const uint2 h0 = v.H[kh * 2], h1 = v.H[kh * 2 + 1];
    const uint2 l0 = v.L[kh * 2], l1 = v.L[kh * 2 + 1];
    const u32 hxA0 = __shfl((int)h0.x, A, 64), hyA0 = __shfl((int)h0.y, A, 64);
    const u32 hxB0 = __shfl((int)h0.x, B, 64), hyB0 = __shfl((int)h0.y, B, 64);
    const u32 hxA1 = __shfl((int)h1.x, A, 64), hyA1 = __shfl((int)h1.y, A, 64);
    const u32 hxB1 = __shfl((int)h1.x, B, 64), hyB1 = __shfl((int)h1.y, B, 64);
    bh[kh].x = hiCt ? hxA1 : hxA0; bh[kh].y = hiCt ? hyA1 : hyA0;
    bh[kh].z = hiCt ? hxB1 : hxB0; bh[kh].w = hiCt ? hyB1 : hyB0;
    const u32 lxA0 = __shfl((int)l0.x, A, 64), lyA0 = __shfl((int)l0.y, A, 64);
    const u32 lxB0 = __shfl((int)l0.x, B, 64), lyB0 = __shfl((int)l0.y, B, 64);
    const u32 lxA1 = __shfl((int)l1.x, A, 64), lyA1 = __shfl((int)l1.y, A, 64);
    const u32 lxB1 = __shfl((int)l1.x, B, 64), lyB1 = __shfl((int)l1.y, B, 64);
    bl[kh].x = hiCt ? lxA1 : lxA0; bl[kh].y = hiCt ? lyA1 : lyA0;
    bl[kh].z = hiCt ? lxB1 : lxB0; bl[kh].w = hiCt ? lyB1 : lyB0;
  }
}

// msg = P(edge e) @ child  (deep 16-uint4 load queue, 24 MFMAs)
__device__ __forceinline__ void edgeMsg(const Ctx& c, int e, const uint4 bh[2],
                                        const uint4 bl[2], f32x4 mo[4]) {
  const f32x4 z = {0.f, 0.f, 0.f, 0.f};
  uint4 ph[4][2], pl[4][2];
  const size_t pb = ((size_t)(e * 8 + c.m)) << 12;
  #pragma unroll
  for (int ci = 0; ci < 4; ++ci)
    #pragma unroll
    for (int kh = 0; kh < 2; ++kh) {
      const size_t off = pb + (size_t)(ci * 16 + c.ln) * 64 + kh * 32 + c.kq * 8;
      ph[ci][kh] = *(const uint4*)(c.Phi + off);
      pl[ci][kh] = *(const uint4*)(c.Plo + off);
    }
  #pragma unroll
  for (int ci = 0; ci < 4; ++ci) {
    f32x4 a = z;
    #pragma unroll
    for (int kh = 0; kh < 2; ++kh)
      mfma3(a, ph[ci][kh], pl[ci][kh], bh[kh], bl[kh]);
    mo[ci] = a;
  }
}

template <int N> __device__ __forceinline__ NV evalN(const Ctx& c);

template <int C>
__device__ __forceinline__ void childB(const Ctx& c, uint4 bh[2], uint4 bl[2]) {
  if constexpr (C < 32) {
    leafB(c, C, bh, bl);
  } else {
    const NV v = evalN<C>(c);
    nvB(c, v, bh, bl);
  }
}

template <int N>
__device__ __forceinline__ NV evalN(const Ctx& c) {
  constexpr int c0 = 2 * (N - 32);  // child node ids; edge id == child id
  uint4 b0h[2], b0l[2], b1h[2], b1l[2];
  childB<c0>(c, b0h, b0l);
  childB<c0 + 1>(c, b1h, b1l);
  f32x4 m0[4], m1[4];
  edgeMsg(c, c0, b0h, b0l, m0);
  edgeMsg(c, c0 + 1, b1h, b1l, m1);
  NV out;
  #pragma unroll
  for (int ci = 0; ci < 4; ++ci) {
    const f32x4 pr = m0[ci] * m1[ci];
    u16 h[4], l[4];
    split_bf16(pr.x, h[0], l[0]); split_bf16(pr.y, h[1], l[1]);
    split_bf16(pr.z, h[2], l[2]); split_bf16(pr.w, h[3], l[3]);
    out.H[ci].x = h[0] | ((u32)h[1] << 16);
    out.H[ci].y = h[2] | ((u32)h[3] << 16);
    out.L[ci].x = l[0] | ((u32)l[1] << 16);
    out.L[ci].y = l[2] | ((u32)l[3] << 16);
  }
  return out;
}

__global__ __launch_bounds__(64, 1) void k_treedf(
    const float* __restrict__ leaves, const u16* __restrict__ Phi,
    const u16* __restrict__ Plo, const float* __restrict__ ws,
    float* __restrict__ out) {
  const int m = blockIdx.x & 7, ctile = blockIdx.x >> 3;  // 64 ctiles x 16 cols
  const int lane = threadIdx.x & 63;
  Ctx c;
  c.leaves = leaves; c.Phi = Phi; c.Plo = Plo;
  c.ln = lane & 15; c.kq = lane >> 4; c.m = m;
  c.colbase = (size_t)ctile * 16;

  // root (node 62): children 60, 61
  uint4 b0h[2], b0l[2], b1h[2], b1l[2];
  childB<60>(c, b0h, b0l);
  childB<61>(c, b1h, b1l);
  f32x4 m0[4], m1[4];
  edgeMsg(c, 60, b0h, b0l, m0);
  edgeMsg(c, 61, b1h, b1l, m1);

  float v = 0.f;
  #pragma unroll
  for (int ci = 0; ci < 4; ++ci) {
    const f32x4 pr = m0[ci] * m1[ci];
    const f32x4 piv =
        *(const f32x4*)&ws[OFF_PI + (size_t)m * 64 + ci * 16 + c.kq * 4];
    v += pr.x * piv.x + pr.y * piv.y + pr.z * piv.z + pr.w * piv.w;
  }
  v += __shfl_xor(v, 16, 64);
  v += __shfl_xor(v, 32, 64);
  if (lane < 16) out[(c.colbase + c.ln) * 8 + m] = v;
}

extern "C" void kernel_launch(void* const* d_in, const int* in_sizes, int n_in,
                              void* d_out, int out_size, void* d_ws, size_t ws_size,
                              hipStream_t stream) {
  const float* leaves  = (const float*)d_in[0];  // (B, 32, 64)
  const float* R_inv   = (const float*)d_in[1];  // (8, 2016)
  const float* pi_inv  = (const float*)d_in[2];  // (8, 63)
  const float* lengths = (const float*)d_in[3];  // (62,)
  float* out = (float*)d_out;                    // (B, 8)
  float* ws  = (float*)d_ws;

  u16* PBH = (u16*)(ws + OFF_PBH);
  u16* PBL = (u16*)(ws + OFF_PBL);

  hipLaunchKernelGGL(k_pcomb, dim3(256), dim3(512), 0, stream, R_inv, pi_inv,
                     lengths, ws, PBH, PBL);
  hipLaunchKernelGGL(k_treedf, dim3(512), dim3(64), 0, stream, leaves, PBH, PBL,
                     ws, out);
}

// Round 10
// 122.220 us; speedup vs baseline: 2.3220x; 2.3220x over previous
//
#include <hip/hip_runtime.h>

typedef unsigned short u16;
typedef unsigned int u32;
typedef __attribute__((ext_vector_type(8))) __bf16 bf16x8;
typedef __attribute__((ext_vector_type(4))) float f32x4;
typedef __attribute__((ext_vector_type(4))) u32 v4u;

// ---- workspace layout (float offsets) ----
constexpr size_t OFF_PI  = 0;                    // pi fp32 [m][64]
constexpr size_t OFF_PBH = 512;                  // P hi bf16 [e][m][c][d] (u16)
constexpr size_t OFF_PBL = OFF_PBH + 1015808;    // P lo

union FR { uint4 u; bf16x8 v; };

// split x -> hi (RNE bf16) + lo (trunc bf16 of residual)
__device__ __forceinline__ void split_bf16(float x, u16& h, u16& l) {
  u32 b = __float_as_uint(x);
  u32 hb = (b + 0x7fffu + ((b >> 16) & 1u)) & 0xffff0000u;
  h = (u16)(hb >> 16);
  float r = x - __uint_as_float(hb);
  l = (u16)(__float_as_uint(r) >> 16);
}

__device__ __forceinline__ void split8(const f32x4 a, const f32x4 b,
                                       uint4& hi, uint4& lo) {
  u16 h[8], l[8];
  split_bf16(a.x, h[0], l[0]); split_bf16(a.y, h[1], l[1]);
  split_bf16(a.z, h[2], l[2]); split_bf16(a.w, h[3], l[3]);
  split_bf16(b.x, h[4], l[4]); split_bf16(b.y, h[5], l[5]);
  split_bf16(b.z, h[6], l[6]); split_bf16(b.w, h[7], l[7]);
  hi.x = h[0] | ((u32)h[1] << 16); hi.y = h[2] | ((u32)h[3] << 16);
  hi.z = h[4] | ((u32)h[5] << 16); hi.w = h[6] | ((u32)h[7] << 16);
  lo.x = l[0] | ((u32)l[1] << 16); lo.y = l[2] | ((u32)l[3] << 16);
  lo.z = l[4] | ((u32)l[5] << 16); lo.w = l[6] | ((u32)l[7] << 16);
}

__device__ __forceinline__ void mfma3(f32x4& a, const uint4 ah, const uint4 al,
                                      const uint4 bh, const uint4 bl) {
  FR Ah, Al, Bh, Bl;
  Ah.u = ah; Al.u = al; Bh.u = bh; Bl.u = bl;
  a = __builtin_amdgcn_mfma_f32_16x16x32_bf16(Ah.v, Bh.v, a, 0, 0, 0);
  a = __builtin_amdgcn_mfma_f32_16x16x32_bf16(Ah.v, Bl.v, a, 0, 0, 0);
  a = __builtin_amdgcn_mfma_f32_16x16x32_bf16(Al.v, Bh.v, a, 0, 0, 0);
}

// asm global 16B load: opaque to the scheduler -> cannot be sunk/chunked.
// NOTE: consumer must s_waitcnt vmcnt(0) manually before reading the result
// (the compiler does not know this is a load).
__device__ __forceinline__ uint4 gload16(const u16* p) {
  v4u d;
  asm volatile("global_load_dwordx4 %0, %1, off" : "=v"(d) : "v"(p) : "memory");
  union { v4u n; uint4 u; } c;
  c.n = d;
  return c.u;
}

// bf16 hi/lo matrix buffer: 64 rows x 32 dwords hi + 2048 dwords lo; 16B chunk
// j of row r at ((j+r)&7) -> conflict-free b128.  (k_pcomb only)
__device__ __forceinline__ void xt_read2(const u32* b, int row, int chunk,
                                         uint4& hi, uint4& lo) {
  const int dw = (row << 5) + (((chunk + row) & 7) << 2);
  hi = *(const uint4*)&b[dw];
  lo = *(const uint4*)&b[2048 + dw];
}
__device__ __forceinline__ void xt_write4(u32* b, int row, int cp, int half,
                                          const f32x4 v) {
  u16 h[4], l[4];
  split_bf16(v.x, h[0], l[0]); split_bf16(v.y, h[1], l[1]);
  split_bf16(v.z, h[2], l[2]); split_bf16(v.w, h[3], l[3]);
  const int dw = (row << 5) + (((cp + row) & 7) << 2) + half * 2;
  uint2 hh, ll;
  hh.x = h[0] | ((u32)h[1] << 16); hh.y = h[2] | ((u32)h[3] << 16);
  ll.x = l[0] | ((u32)l[1] << 16); ll.y = l[2] | ((u32)l[3] << 16);
  *(uint2*)&b[dw] = hh;
  *(uint2*)&b[2048 + dw] = ll;
}

// ---------------- K1: pi, Q, DEPTH-4 parallel ladder, combine -> P hi/lo ----
// (R7 proven, unchanged.) 256 blocks x 512 threads; m = blk&7, prt = blk>>3.
__global__ __launch_bounds__(512, 2) void k_pcomb(
    const float* __restrict__ R_inv, const float* __restrict__ pi_inv,
    const float* __restrict__ lengths, float* __restrict__ ws,
    u16* __restrict__ PBH, u16* __restrict__ PBL) {
  const int m = blockIdx.x & 7, prt = blockIdx.x >> 3;
  const int tid = threadIdx.x, lane = tid & 63, w = tid >> 6;  // 8 waves
  const int ln = lane & 15, kq = lane >> 4;
  __shared__ float pis[64];
  __shared__ float n2s;
  __shared__ __align__(16) float Qs[64 * 68];
  __shared__ __align__(16) u32 PB[8][4096];  // row Q1,Q2,Q4,Q8; col Q1,Q2,Q3,Q4

  if (tid < 64) {
    float p = (tid < 63) ? pi_inv[m * 63 + tid] : 0.f;
    float v = p * p;
    #pragma unroll
    for (int off = 32; off; off >>= 1) v += __shfl_down(v, off, 64);
    if (tid == 0) n2s = v;
  }
  __syncthreads();
  if (tid < 64) {
    const float den = n2s + 1.f;
    const float x = (tid < 63) ? 2.f * pi_inv[m * 63 + tid] / den
                               : (n2s - 1.f) / den;
    const float pv = x * x;
    pis[tid] = pv;
    if (prt == 0) ws[OFF_PI + (size_t)m * 64 + tid] = pv;
  }
  __syncthreads();
  for (int idx = tid; idx < 4096; idx += 512) {
    const int i = idx >> 6, j = idx & 63;
    float q = 0.f;
    if (i != j) {
      const int a = min(i, j), b = max(i, j);
      const int kk = a * (127 - a) / 2 + (b - a - 1);
      q = expf(R_inv[m * 2016 + kk]) * pis[j];
    }
    Qs[i * 68 + j] = q;
  }
  __syncthreads();
  if (tid < 64) {
    float s = 0.f;
    #pragma unroll 4
    for (int j4 = 0; j4 < 64; j4 += 4) {
      const f32x4 q = *(const f32x4*)&Qs[tid * 68 + j4];
      s += q.x + q.y + q.z + q.w;
    }
    Qs[tid * 68 + tid] = -s;
  }
  __syncthreads();

  float q[12][2][4];
  #pragma unroll
  for (int tt = 0; tt < 2; ++tt) {
    const int T = w + tt * 8, ct = T >> 2, bt = T & 3;
    #pragma unroll
    for (int r = 0; r < 4; ++r)
      q[0][tt][r] = Qs[(ct * 16 + kq * 4 + r) * 68 + bt * 16 + ln];
  }
  {
    const int i = tid >> 3, c = tid & 7;
    const f32x4 a = *(const f32x4*)&Qs[i * 68 + c * 8];
    const f32x4 b = *(const f32x4*)&Qs[i * 68 + c * 8 + 4];
    uint4 h, l;
    split8(a, b, h, l);
    const int dw = (i << 5) + (((c + i) & 7) << 2);
    *(uint4*)&PB[0][dw] = h;
    *(uint4*)&PB[0][2048 + dw] = l;
    const int j = i;
    f32x4 ca, cb;
    ca.x = Qs[(c * 8 + 0) * 68 + j]; ca.y = Qs[(c * 8 + 1) * 68 + j];
    ca.z = Qs[(c * 8 + 2) * 68 + j]; ca.w = Qs[(c * 8 + 3) * 68 + j];
    cb.x = Qs[(c * 8 + 4) * 68 + j]; cb.y = Qs[(c * 8 + 5) * 68 + j];
    cb.z = Qs[(c * 8 + 6) * 68 + j]; cb.w = Qs[(c * 8 + 7) * 68 + j];
    split8(ca, cb, h, l);
    *(uint4*)&PB[4][dw] = h;
    *(uint4*)&PB[4][2048 + dw] = l;
  }
  __syncthreads();

  const f32x4 z = {0.f, 0.f, 0.f, 0.f};
  auto tileP = [&](const u32* RX, const u32* CY, int T) -> f32x4 {
    const int ct = T >> 2, bt = T & 3;
    uint4 ah[2], al[2], bh[2], bl[2];
    #pragma unroll
    for (int kh = 0; kh < 2; ++kh) {
      xt_read2(RX, ct * 16 + ln, kh * 4 + kq, ah[kh], al[kh]);
      xt_read2(CY, bt * 16 + ln, kh * 4 + kq, bh[kh], bl[kh]);
    }
    f32x4 a = z;
    #pragma unroll
    for (int kh = 0; kh < 2; ++kh) mfma3(a, ah[kh], al[kh], bh[kh], bl[kh]);
    return a;
  };
  auto tileT = [&](const u32* RX, const u32* CY, int T) -> f32x4 {
    const int ct = T >> 2, bt = T & 3;
    uint4 ah[2], al[2], bh[2], bl[2];
    #pragma unroll
    for (int kh = 0; kh < 2; ++kh) {
      xt_read2(CY, ct * 16 + ln, kh * 4 + kq, ah[kh], al[kh]);
      xt_read2(RX, bt * 16 + ln, kh * 4 + kq, bh[kh], bl[kh]);
    }
    f32x4 a = z;
    #pragma unroll
    for (int kh = 0; kh < 2; ++kh) mfma3(a, ah[kh], al[kh], bh[kh], bl[kh]);
    return a;
  };
  auto wbuf = [&](u32* dst, int T, const f32x4 a) {
    const int ct = T >> 2, bt = T & 3;
    xt_write4(dst, bt * 16 + ln, 2 * ct + (kq >> 1), kq & 1, a);
  };

  #pragma unroll
  for (int tt = 0; tt < 2; ++tt) {
    const int T = w + tt * 8;
    const f32x4 a = tileP(PB[0], PB[4], T);
    #pragma unroll
    for (int r = 0; r < 4; ++r) q[1][tt][r] = a[r];
    wbuf(PB[5], T, a);
    wbuf(PB[1], T, tileT(PB[0], PB[4], T));
  }
  __syncthreads();
  #pragma unroll
  for (int tt = 0; tt < 2; ++tt) {
    const int T = w + tt * 8;
    const f32x4 a3 = tileP(PB[1], PB[4], T);
    const f32x4 a4 = tileP(PB[1], PB[5], T);
    #pragma unroll
    for (int r = 0; r < 4; ++r) { q[2][tt][r] = a3[r]; q[3][tt][r] = a4[r]; }
    wbuf(PB[6], T, a3);
    wbuf(PB[7], T, a4);
    wbuf(PB[2], T, tileT(PB[1], PB[5], T));
  }
  __syncthreads();
  #pragma unroll
  for (int tt = 0; tt < 2; ++tt) {
    const int T = w + tt * 8;
    const f32x4 a5 = tileP(PB[2], PB[4], T);
    const f32x4 a6 = tileP(PB[2], PB[5], T);
    const f32x4 a7 = tileP(PB[2], PB[6], T);
    const f32x4 a8 = tileP(PB[2], PB[7], T);
    #pragma unroll
    for (int r = 0; r < 4; ++r) {
      q[4][tt][r] = a5[r]; q[5][tt][r] = a6[r];
      q[6][tt][r] = a7[r]; q[7][tt][r] = a8[r];
    }
    wbuf(PB[3], T, tileT(PB[2], PB[7], T));
  }
  __syncthreads();
  #pragma unroll
  for (int tt = 0; tt < 2; ++tt) {
    const int T = w + tt * 8;
    const f32x4 a9  = tileP(PB[3], PB[4], T);
    const f32x4 a10 = tileP(PB[3], PB[5], T);
    const f32x4 a11 = tileP(PB[3], PB[6], T);
    const f32x4 a12 = tileP(PB[3], PB[7], T);
    #pragma unroll
    for (int r = 0; r < 4; ++r) {
      q[8][tt][r] = a9[r];  q[9][tt][r] = a10[r];
      q[10][tt][r] = a11[r]; q[11][tt][r] = a12[r];
    }
  }

  #pragma unroll
  for (int ei = 0; ei < 2; ++ei) {
    const int e = prt * 2 + ei;
    if (e >= 62) break;
    const float t = lengths[e];
    const size_t base = ((size_t)e * 8 + m) << 12;
    #pragma unroll
    for (int tt = 0; tt < 2; ++tt) {
      const int T = w + tt * 8, ct = T >> 2, bt = T & 3;
      float av[4];
      #pragma unroll
      for (int r = 0; r < 4; ++r)
        av[r] = (ct == bt && ln == kq * 4 + r) ? 1.f : 0.f;
      float cf = 1.f;
      #pragma unroll
      for (int k = 1; k <= 12; ++k) {
        cf *= t / (float)k;
        #pragma unroll
        for (int r = 0; r < 4; ++r) av[r] = fmaf(cf, q[k - 1][tt][r], av[r]);
      }
      #pragma unroll
      for (int r = 0; r < 4; ++r) {
        u16 h, l;
        split_bf16(av[r], h, l);
        const size_t off =
            base + (size_t)(ct * 16 + kq * 4 + r) * 64 + bt * 16 + ln;
        PBH[off] = h;
        PBL[off] = l;
      }
    }
  }
}

// ---------------- K2: fused tree + final dot, asm-forced P-load queue -------
// Structure = proven R0/R7 (256 blocks x 512 thr, 131 KB LDS, slot map,
// barriers, numerics all byte-identical). ONE change: each sibling's 16
// P-fragment loads are issued via asm volatile global_load_dwordx4 (opaque to
// the scheduler -> cannot be sunk into shallow chunks; this chunking at
// VGPR=96 was the measured R0-R9 latency bottleneck), then one manual
// s_waitcnt vmcnt(0) + sched_barrier(0) before that sibling's MFMA block.
// Compiler-emitted waitcnts for its own loads become over-conservative with
// asm loads in the HW queue -- never under-conservative -> correct.
__global__ __launch_bounds__(512, 2) void k_tree(
    const float* __restrict__ leaves, const u16* __restrict__ Phi,
    const u16* __restrict__ Plo, const float* __restrict__ ws,
    float* __restrict__ out) {
  const int m = blockIdx.x & 7, btile = blockIdx.x >> 3;
  const int tid = threadIdx.x, lane = tid & 63, w = tid >> 6;
  const int ln = lane & 15, kq = lane >> 4;
  __shared__ __align__(16) u32 slots[16 * 2048];  // 16 x (32 rows x 64 dwords)
  __shared__ float psum[2][4][16];
  const f32x4 z = {0.f, 0.f, 0.f, 0.f};

  auto node_read = [&](int slot, int row, int kh, uint4& bh, uint4& bl) {
    const int jc = kh * 8 + kq * 2;
    const u32* b = &slots[slot * 2048 + row * 64];
    const uint4 A = *(const uint4*)&b[((jc + row) & 15) << 2];
    const uint4 B = *(const uint4*)&b[((jc + 1 + row) & 15) << 2];
    bh.x = A.x; bh.y = A.y; bh.z = B.x; bh.w = B.y;
    bl.x = A.z; bl.y = A.w; bl.z = B.z; bl.w = B.w;
  };
  auto node_write = [&](int slot, int row, int jc, const f32x4 v) {
    u16 h[4], l[4];
    split_bf16(v.x, h[0], l[0]); split_bf16(v.y, h[1], l[1]);
    split_bf16(v.z, h[2], l[2]); split_bf16(v.w, h[3], l[3]);
    uint4 pk;
    pk.x = h[0] | ((u32)h[1] << 16); pk.y = h[2] | ((u32)h[3] << 16);
    pk.z = l[0] | ((u32)l[1] << 16); pk.w = l[2] | ((u32)l[3] << 16);
    *(uint4*)&slots[slot * 2048 + row * 64 + (((jc + row) & 15) << 2)] = pk;
  };

  auto do_pair = [&](int eb, int p, int s0, int s1, int outSlot, int bt0,
                     int nbt, int ct0, int nct, bool leaf, f32x4* rootout) {
    // phase 1: ALL B-fragments (unchanged)
    uint4 bfh[2][2][2], bfl[2][2][2];  // [sib][bi][kh]
    #pragma unroll
    for (int s = 0; s < 2; ++s)
      #pragma unroll
      for (int bi = 0; bi < 2; ++bi) {
        if (bi >= nbt) continue;
        const int row = (bt0 + bi) * 16 + ln;
        #pragma unroll
        for (int kh = 0; kh < 2; ++kh) {
          if (leaf) {
            const float* g = leaves + (size_t)(btile * 32 + row) * 2048 +
                             (size_t)(eb + 2 * p + s) * 64 + kh * 32 + kq * 8;
            const f32x4 xa = *(const f32x4*)g;
            const f32x4 xb = *(const f32x4*)(g + 4);
            split8(xa, xb, bfh[s][bi][kh], bfl[s][bi][kh]);
          } else {
            node_read(s ? s1 : s0, row, kh, bfh[s][bi][kh], bfl[s][bi][kh]);
          }
        }
      }
    // per sibling: asm-issue the FULL 16-load P queue, drain once, MFMA
    f32x4 a0[4][2];
    #pragma unroll
    for (int s = 0; s < 2; ++s) {
      const size_t pb = ((size_t)(eb + 2 * p + s) * 8 + m) << 12;
      uint4 ph[4][2], pl[4][2];
      #pragma unroll
      for (int ci = 0; ci < 4; ++ci) {
        if (ci >= nct) continue;
        #pragma unroll
        for (int kh = 0; kh < 2; ++kh) {
          const size_t off =
              pb + (size_t)((ct0 + ci) * 16 + ln) * 64 + kh * 32 + kq * 8;
          ph[ci][kh] = gload16(Phi + off);
          pl[ci][kh] = gload16(Plo + off);
        }
      }
      asm volatile("s_waitcnt vmcnt(0)" ::: "memory");
      __builtin_amdgcn_sched_barrier(0);
      #pragma unroll
      for (int ci = 0; ci < 4; ++ci) {
        if (ci >= nct) continue;
        #pragma unroll
        for (int bi = 0; bi < 2; ++bi) {
          if (bi >= nbt) continue;
          f32x4 a = z;
          #pragma unroll
          for (int kh = 0; kh < 2; ++kh)
            mfma3(a, ph[ci][kh], pl[ci][kh], bfh[s][bi][kh], bfl[s][bi][kh]);
          if (s == 0) {
            a0[ci][bi] = a;
          } else {
            const f32x4 pr = a0[ci][bi] * a;
            if (rootout)
              *rootout = pr;
            else
              node_write(outSlot, (bt0 + bi) * 16 + ln, (ct0 + ci) * 4 + kq,
                         pr);
          }
        }
      }
    }
  };

  // L0: 16 pairs (leaves), 2 per wave -> slots 0..15
  do_pair(0, w, -1, -1, w, 0, 2, 0, 4, true, nullptr);
  do_pair(0, w + 8, -1, -1, w + 8, 0, 2, 0, 4, true, nullptr);
  __syncthreads();
  // L1: 8 pairs, 1/wave: slots (2w, 2w+1) -> 2w
  do_pair(32, w, 2 * w, 2 * w + 1, 2 * w, 0, 2, 0, 4, false, nullptr);
  __syncthreads();
  // L2: 4 pairs x 2 bi-waves: slots (4j, 4j+2) -> 4j
  {
    const int j = w >> 1, bi = w & 1;
    do_pair(48, j, 4 * j, 4 * j + 2, 4 * j, bi, 1, 0, 4, false, nullptr);
  }
  __syncthreads();
  // L3: 2 pairs x (bi, ct-half): slots (8j, 8j+4) -> 8j+1
  {
    const int j = w >> 2, bi = w & 1, ch = (w >> 1) & 1;
    do_pair(56, j, 8 * j, 8 * j + 4, 8 * j + 1, bi, 1, ch * 2, 2, false,
            nullptr);
  }
  __syncthreads();
  // L4 root: slots (1, 9); 8 waves = (bi, ct); fused dot with pi
  {
    f32x4 pr = z;
    do_pair(60, 0, 1, 9, -1, w & 1, 1, w >> 1, 1, false, &pr);
    const f32x4 piv =
        *(const f32x4*)&ws[OFF_PI + (size_t)m * 64 + (w >> 1) * 16 + kq * 4];
    float v = pr.x * piv.x + pr.y * piv.y + pr.z * piv.z + pr.w * piv.w;
    v += __shfl_xor(v, 16, 64);
    v += __shfl_xor(v, 32, 64);
    if (lane < 16) psum[w & 1][w >> 1][lane] = v;
  }
  __syncthreads();
  if (tid < 32) {
    const int bi = tid >> 4, bb = tid & 15;
    out[(size_t)(btile * 32 + tid) * 8 + m] =
        psum[bi][0][bb] + psum[bi][1][bb] + psum[bi][2][bb] + psum[bi][3][bb];
  }
}

extern "C" void kernel_launch(void* const* d_in, const int* in_sizes, int n_in,
                              void* d_out, int out_size, void* d_ws, size_t ws_size,
                              hipStream_t stream) {
  const float* leaves  = (const float*)d_in[0];  // (B, 32, 64)
  const float* R_inv   = (const float*)d_in[1];  // (8, 2016)
  const float* pi_inv  = (const float*)d_in[2];  // (8, 63)
  const float* lengths = (const float*)d_in[3];  // (62,)
  float* out = (float*)d_out;                    // (B, 8)
  float* ws  = (float*)d_ws;

  u16* PBH = (u16*)(ws + OFF_PBH);
  u16* PBL = (u16*)(ws + OFF_PBL);

  hipLaunchKernelGGL(k_pcomb, dim3(256), dim3(512), 0, stream, R_inv, pi_inv,
                     lengths, ws, PBH, PBL);
  hipLaunchKernelGGL(k_tree, dim3(256), dim3(512), 0, stream, leaves, PBH, PBL,
                     ws, out);
}

// Round 11
// 119.597 us; speedup vs baseline: 2.3729x; 1.0219x over previous
//
#include <hip/hip_runtime.h>

typedef unsigned short u16;
typedef unsigned int u32;
typedef __attribute__((ext_vector_type(8))) __bf16 bf16x8;
typedef __attribute__((ext_vector_type(4))) float f32x4;

// ---- workspace layout (float offsets) ----
constexpr size_t OFF_PI  = 0;                    // pi fp32 [m][64]
constexpr size_t OFF_PBH = 512;                  // P hi bf16 [e][m][c][d] (u16)
constexpr size_t OFF_PBL = OFF_PBH + 1015808;    // P lo

union FR { uint4 u; bf16x8 v; };

// split x -> hi (RNE bf16) + lo (trunc bf16 of residual)
__device__ __forceinline__ void split_bf16(float x, u16& h, u16& l) {
  u32 b = __float_as_uint(x);
  u32 hb = (b + 0x7fffu + ((b >> 16) & 1u)) & 0xffff0000u;
  h = (u16)(hb >> 16);
  float r = x - __uint_as_float(hb);
  l = (u16)(__float_as_uint(r) >> 16);
}

__device__ __forceinline__ void split8(const f32x4 a, const f32x4 b,
                                       uint4& hi, uint4& lo) {
  u16 h[8], l[8];
  split_bf16(a.x, h[0], l[0]); split_bf16(a.y, h[1], l[1]);
  split_bf16(a.z, h[2], l[2]); split_bf16(a.w, h[3], l[3]);
  split_bf16(b.x, h[4], l[4]); split_bf16(b.y, h[5], l[5]);
  split_bf16(b.z, h[6], l[6]); split_bf16(b.w, h[7], l[7]);
  hi.x = h[0] | ((u32)h[1] << 16); hi.y = h[2] | ((u32)h[3] << 16);
  hi.z = h[4] | ((u32)h[5] << 16); hi.w = h[6] | ((u32)h[7] << 16);
  lo.x = l[0] | ((u32)l[1] << 16); lo.y = l[2] | ((u32)l[3] << 16);
  lo.z = l[4] | ((u32)l[5] << 16); lo.w = l[6] | ((u32)l[7] << 16);
}

__device__ __forceinline__ void mfma3(f32x4& a, const uint4 ah, const uint4 al,
                                      const uint4 bh, const uint4 bl) {
  FR Ah, Al, Bh, Bl;
  Ah.u = ah; Al.u = al; Bh.u = bh; Bl.u = bl;
  a = __builtin_amdgcn_mfma_f32_16x16x32_bf16(Ah.v, Bh.v, a, 0, 0, 0);
  a = __builtin_amdgcn_mfma_f32_16x16x32_bf16(Ah.v, Bl.v, a, 0, 0, 0);
  a = __builtin_amdgcn_mfma_f32_16x16x32_bf16(Al.v, Bh.v, a, 0, 0, 0);
}

// bf16 hi/lo matrix buffer: 64 rows x 32 dwords hi + 2048 dwords lo; 16B chunk
// j of row r at ((j+r)&7) -> conflict-free b128.
__device__ __forceinline__ void xt_read2(const u32* b, int row, int chunk,
                                         uint4& hi, uint4& lo) {
  const int dw = (row << 5) + (((chunk + row) & 7) << 2);
  hi = *(const uint4*)&b[dw];
  lo = *(const uint4*)&b[2048 + dw];
}
__device__ __forceinline__ void xt_write4(u32* b, int row, int cp, int half,
                                          const f32x4 v) {
  u16 h[4], l[4];
  split_bf16(v.x, h[0], l[0]); split_bf16(v.y, h[1], l[1]);
  split_bf16(v.z, h[2], l[2]); split_bf16(v.w, h[3], l[3]);
  const int dw = (row << 5) + (((cp + row) & 7) << 2) + half * 2;
  uint2 hh, ll;
  hh.x = h[0] | ((u32)h[1] << 16); hh.y = h[2] | ((u32)h[3] << 16);
  ll.x = l[0] | ((u32)l[1] << 16); ll.y = l[2] | ((u32)l[3] << 16);
  *(uint2*)&b[dw] = hh;
  *(uint2*)&b[2048 + dw] = ll;
}

// ---------------- K1: pi, Q, DEPTH-4 parallel ladder, combine -> P hi/lo ----
// (R7 proven.) 256 blocks x 512 threads; m = blk&7 (XCD-affine), prt = blk>>3.
// Ladder depth 4: Q2 | {Q3,Q4} | {Q5..Q8} | {Q9..Q12}; accumulators stay in
// registers in MFMA lane layout; 3 level barriers.
__global__ __launch_bounds__(512, 2) void k_pcomb(
    const float* __restrict__ R_inv, const float* __restrict__ pi_inv,
    const float* __restrict__ lengths, float* __restrict__ ws,
    u16* __restrict__ PBH, u16* __restrict__ PBL) {
  const int m = blockIdx.x & 7, prt = blockIdx.x >> 3;
  const int tid = threadIdx.x, lane = tid & 63, w = tid >> 6;  // 8 waves
  const int ln = lane & 15, kq = lane >> 4;
  __shared__ float pis[64];
  __shared__ float n2s;
  __shared__ __align__(16) float Qs[64 * 68];
  __shared__ __align__(16) u32 PB[8][4096];  // row Q1,Q2,Q4,Q8; col Q1,Q2,Q3,Q4

  if (tid < 64) {
    float p = (tid < 63) ? pi_inv[m * 63 + tid] : 0.f;
    float v = p * p;
    #pragma unroll
    for (int off = 32; off; off >>= 1) v += __shfl_down(v, off, 64);
    if (tid == 0) n2s = v;
  }
  __syncthreads();
  if (tid < 64) {
    const float den = n2s + 1.f;
    const float x = (tid < 63) ? 2.f * pi_inv[m * 63 + tid] / den
                               : (n2s - 1.f) / den;
    const float pv = x * x;
    pis[tid] = pv;
    if (prt == 0) ws[OFF_PI + (size_t)m * 64 + tid] = pv;
  }
  __syncthreads();
  for (int idx = tid; idx < 4096; idx += 512) {
    const int i = idx >> 6, j = idx & 63;
    float q = 0.f;
    if (i != j) {
      const int a = min(i, j), b = max(i, j);
      const int kk = a * (127 - a) / 2 + (b - a - 1);
      q = expf(R_inv[m * 2016 + kk]) * pis[j];
    }
    Qs[i * 68 + j] = q;
  }
  __syncthreads();
  if (tid < 64) {
    float s = 0.f;
    #pragma unroll 4
    for (int j4 = 0; j4 < 64; j4 += 4) {
      const f32x4 q = *(const f32x4*)&Qs[tid * 68 + j4];
      s += q.x + q.y + q.z + q.w;
    }
    Qs[tid * 68 + tid] = -s;
  }
  __syncthreads();

  // canonical Q^k in MFMA layout: q[k-1][tt][r] =
  //   Q^k[ct*16+kq*4+r][bt*16+ln] for tile T = w + 8*tt, ct=T>>2, bt=T&3.
  float q[12][2][4];
  #pragma unroll
  for (int tt = 0; tt < 2; ++tt) {
    const int T = w + tt * 8, ct = T >> 2, bt = T & 3;
    #pragma unroll
    for (int r = 0; r < 4; ++r)
      q[0][tt][r] = Qs[(ct * 16 + kq * 4 + r) * 68 + bt * 16 + ln];
  }
  // stage Q1: row layout -> PB[0], col layout -> PB[4]
  {
    const int i = tid >> 3, c = tid & 7;
    const f32x4 a = *(const f32x4*)&Qs[i * 68 + c * 8];
    const f32x4 b = *(const f32x4*)&Qs[i * 68 + c * 8 + 4];
    uint4 h, l;
    split8(a, b, h, l);
    const int dw = (i << 5) + (((c + i) & 7) << 2);
    *(uint4*)&PB[0][dw] = h;
    *(uint4*)&PB[0][2048 + dw] = l;
    const int j = i;
    f32x4 ca, cb;
    ca.x = Qs[(c * 8 + 0) * 68 + j]; ca.y = Qs[(c * 8 + 1) * 68 + j];
    ca.z = Qs[(c * 8 + 2) * 68 + j]; ca.w = Qs[(c * 8 + 3) * 68 + j];
    cb.x = Qs[(c * 8 + 4) * 68 + j]; cb.y = Qs[(c * 8 + 5) * 68 + j];
    cb.z = Qs[(c * 8 + 6) * 68 + j]; cb.w = Qs[(c * 8 + 7) * 68 + j];
    split8(ca, cb, h, l);
    *(uint4*)&PB[4][dw] = h;
    *(uint4*)&PB[4][2048 + dw] = l;
  }
  __syncthreads();

  const f32x4 z = {0.f, 0.f, 0.f, 0.f};
  // tile (ct,bt) of RX·CY (row-layout RX, col-layout CY)
  auto tileP = [&](const u32* RX, const u32* CY, int T) -> f32x4 {
    const int ct = T >> 2, bt = T & 3;
    uint4 ah[2], al[2], bh[2], bl[2];
    #pragma unroll
    for (int kh = 0; kh < 2; ++kh) {
      xt_read2(RX, ct * 16 + ln, kh * 4 + kq, ah[kh], al[kh]);
      xt_read2(CY, bt * 16 + ln, kh * 4 + kq, bh[kh], bl[kh]);
    }
    f32x4 a = z;
    #pragma unroll
    for (int kh = 0; kh < 2; ++kh) mfma3(a, ah[kh], al[kh], bh[kh], bl[kh]);
    return a;
  };
  // tile of the transpose product (for row-layout writes of RX·CY)
  auto tileT = [&](const u32* RX, const u32* CY, int T) -> f32x4 {
    const int ct = T >> 2, bt = T & 3;
    uint4 ah[2], al[2], bh[2], bl[2];
    #pragma unroll
    for (int kh = 0; kh < 2; ++kh) {
      xt_read2(CY, ct * 16 + ln, kh * 4 + kq, ah[kh], al[kh]);
      xt_read2(RX, bt * 16 + ln, kh * 4 + kq, bh[kh], bl[kh]);
    }
    f32x4 a = z;
    #pragma unroll
    for (int kh = 0; kh < 2; ++kh) mfma3(a, ah[kh], al[kh], bh[kh], bl[kh]);
    return a;
  };
  auto wbuf = [&](u32* dst, int T, const f32x4 a) {
    const int ct = T >> 2, bt = T & 3;
    xt_write4(dst, bt * 16 + ln, 2 * ct + (kq >> 1), kq & 1, a);
  };

  // ---- L1: Q2 = Q1*Q1 (keep canonical; write col->PB5, row->PB1) ----
  #pragma unroll
  for (int tt = 0; tt < 2; ++tt) {
    const int T = w + tt * 8;
    const f32x4 a = tileP(PB[0], PB[4], T);
    #pragma unroll
    for (int r = 0; r < 4; ++r) q[1][tt][r] = a[r];
    wbuf(PB[5], T, a);
    wbuf(PB[1], T, tileT(PB[0], PB[4], T));
  }
  __syncthreads();
  // ---- L2: Q3 = Q2*Q1 (col->PB6), Q4 = Q2*Q2 (col->PB7, row->PB2) ----
  #pragma unroll
  for (int tt = 0; tt < 2; ++tt) {
    const int T = w + tt * 8;
    const f32x4 a3 = tileP(PB[1], PB[4], T);
    const f32x4 a4 = tileP(PB[1], PB[5], T);
    #pragma unroll
    for (int r = 0; r < 4; ++r) { q[2][tt][r] = a3[r]; q[3][tt][r] = a4[r]; }
    wbuf(PB[6], T, a3);
    wbuf(PB[7], T, a4);
    wbuf(PB[2], T, tileT(PB[1], PB[5], T));
  }
  __syncthreads();
  // ---- L3: Q5..Q8 = Q4*{Q1,Q2,Q3,Q4} (Q8 row->PB3) ----
  #pragma unroll
  for (int tt = 0; tt < 2; ++tt) {
    const int T = w + tt * 8;
    const f32x4 a5 = tileP(PB[2], PB[4], T);
    const f32x4 a6 = tileP(PB[2], PB[5], T);
    const f32x4 a7 = tileP(PB[2], PB[6], T);
    const f32x4 a8 = tileP(PB[2], PB[7], T);
    #pragma unroll
    for (int r = 0; r < 4; ++r) {
      q[4][tt][r] = a5[r]; q[5][tt][r] = a6[r];
      q[6][tt][r] = a7[r]; q[7][tt][r] = a8[r];
    }
    wbuf(PB[3], T, tileT(PB[2], PB[7], T));
  }
  __syncthreads();
  // ---- L4: Q9..Q12 = Q8*{Q1,Q2,Q3,Q4} (registers only) ----
  #pragma unroll
  for (int tt = 0; tt < 2; ++tt) {
    const int T = w + tt * 8;
    const f32x4 a9  = tileP(PB[3], PB[4], T);
    const f32x4 a10 = tileP(PB[3], PB[5], T);
    const f32x4 a11 = tileP(PB[3], PB[6], T);
    const f32x4 a12 = tileP(PB[3], PB[7], T);
    #pragma unroll
    for (int r = 0; r < 4; ++r) {
      q[8][tt][r] = a9[r];  q[9][tt][r] = a10[r];
      q[10][tt][r] = a11[r]; q[11][tt][r] = a12[r];
    }
  }

  // ---- combine: this part's 2 edges, all in registers (MFMA layout) ----
  #pragma unroll
  for (int ei = 0; ei < 2; ++ei) {
    const int e = prt * 2 + ei;
    if (e >= 62) break;
    const float t = lengths[e];
    const size_t base = ((size_t)e * 8 + m) << 12;
    #pragma unroll
    for (int tt = 0; tt < 2; ++tt) {
      const int T = w + tt * 8, ct = T >> 2, bt = T & 3;
      float av[4];
      #pragma unroll
      for (int r = 0; r < 4; ++r)
        av[r] = (ct == bt && ln == kq * 4 + r) ? 1.f : 0.f;
      float cf = 1.f;
      #pragma unroll
      for (int k = 1; k <= 12; ++k) {
        cf *= t / (float)k;
        #pragma unroll
        for (int r = 0; r < 4; ++r) av[r] = fmaf(cf, q[k - 1][tt][r], av[r]);
      }
      #pragma unroll
      for (int r = 0; r < 4; ++r) {
        u16 h, l;
        split_bf16(av[r], h, l);
        const size_t off =
            base + (size_t)(ct * 16 + kq * 4 + r) * 64 + bt * 16 + ln;
        PBH[off] = h;
        PBL[off] = l;
      }
    }
  }
}

// ---------------- K2: fully-fused tree + final dot (proven 48.5us) ---------
// 256 blocks = (m = blk&7 [XCD], btile of 32 cols) x 8 waves.
// Nodes in LDS as interleaved h4|l4 16B chunks (16 chunks/row, XOR-swizzled):
// write = 1 b128, read = 2 b128 + register recombine (no VALU split).
// Slot map: node 32+i -> slot i (L0); 48+j -> 2j (L1); 56+j -> 4j (L2);
// 60+j -> 8j+1 (L3); root reads slots 1,9. Intra-level safety: each slot's
// readers either own the write (same-wave DS ordering) or touch disjoint rows.
__global__ __launch_bounds__(512, 2) void k_tree(
    const float* __restrict__ leaves, const u16* __restrict__ Phi,
    const u16* __restrict__ Plo, const float* __restrict__ ws,
    float* __restrict__ out) {
  const int m = blockIdx.x & 7, btile = blockIdx.x >> 3;
  const int tid = threadIdx.x, lane = tid & 63, w = tid >> 6;
  const int ln = lane & 15, kq = lane >> 4;
  __shared__ __align__(16) u32 slots[16 * 2048];  // 16 x (32 rows x 64 dwords)
  __shared__ float psum[2][4][16];
  const f32x4 z = {0.f, 0.f, 0.f, 0.f};

  auto node_read = [&](int slot, int row, int kh, uint4& bh, uint4& bl) {
    const int jc = kh * 8 + kq * 2;
    const u32* b = &slots[slot * 2048 + row * 64];
    const uint4 A = *(const uint4*)&b[((jc + row) & 15) << 2];
    const uint4 B = *(const uint4*)&b[((jc + 1 + row) & 15) << 2];
    bh.x = A.x; bh.y = A.y; bh.z = B.x; bh.w = B.y;
    bl.x = A.z; bl.y = A.w; bl.z = B.z; bl.w = B.w;
  };
  auto node_write = [&](int slot, int row, int jc, const f32x4 v) {
    u16 h[4], l[4];
    split_bf16(v.x, h[0], l[0]); split_bf16(v.y, h[1], l[1]);
    split_bf16(v.z, h[2], l[2]); split_bf16(v.w, h[3], l[3]);
    uint4 pk;
    pk.x = h[0] | ((u32)h[1] << 16); pk.y = h[2] | ((u32)h[3] << 16);
    pk.z = l[0] | ((u32)l[1] << 16); pk.w = l[2] | ((u32)l[3] << 16);
    *(uint4*)&slots[slot * 2048 + row * 64 + (((jc + row) & 15) << 2)] = pk;
  };

  auto do_pair = [&](int eb, int p, int s0, int s1, int outSlot, int bt0,
                     int nbt, int ct0, int nct, bool leaf, f32x4* rootout) {
    // phase 1: ALL B-fragments
    uint4 bfh[2][2][2], bfl[2][2][2];  // [sib][bi][kh]
    #pragma unroll
    for (int s = 0; s < 2; ++s)
      #pragma unroll
      for (int bi = 0; bi < 2; ++bi) {
        if (bi >= nbt) continue;
        const int row = (bt0 + bi) * 16 + ln;
        #pragma unroll
        for (int kh = 0; kh < 2; ++kh) {
          if (leaf) {
            const float* g = leaves + (size_t)(btile * 32 + row) * 2048 +
                             (size_t)(eb + 2 * p + s) * 64 + kh * 32 + kq * 8;
            const f32x4 xa = *(const f32x4*)g;
            const f32x4 xb = *(const f32x4*)(g + 4);
            split8(xa, xb, bfh[s][bi][kh], bfl[s][bi][kh]);
          } else {
            node_read(s ? s1 : s0, row, kh, bfh[s][bi][kh], bfl[s][bi][kh]);
          }
        }
      }
    // phase 2: ALL P-fragments for both siblings (deep load queue)
    uint4 ph[2][4][2], pl[2][4][2];  // [sib][ci][kh]
    #pragma unroll
    for (int s = 0; s < 2; ++s) {
      const size_t pb = ((size_t)(eb + 2 * p + s) * 8 + m) << 12;
      #pragma unroll
      for (int ci = 0; ci < 4; ++ci) {
        if (ci >= nct) continue;
        #pragma unroll
        for (int kh = 0; kh < 2; ++kh) {
          const size_t off =
              pb + (size_t)((ct0 + ci) * 16 + ln) * 64 + kh * 32 + kq * 8;
          ph[s][ci][kh] = *(const uint4*)(Phi + off);
          pl[s][ci][kh] = *(const uint4*)(Plo + off);
        }
      }
    }
    // phase 3: MFMA sibling 0
    f32x4 a0[4][2];
    #pragma unroll
    for (int ci = 0; ci < 4; ++ci) {
      if (ci >= nct) continue;
      #pragma unroll
      for (int bi = 0; bi < 2; ++bi) {
        if (bi >= nbt) continue;
        f32x4 a = z;
        #pragma unroll
        for (int kh = 0; kh < 2; ++kh)
          mfma3(a, ph[0][ci][kh], pl[0][ci][kh], bfh[0][bi][kh], bfl[0][bi][kh]);
        a0[ci][bi] = a;
      }
    }
    // phase 4: MFMA sibling 1, product, emit
    #pragma unroll
    for (int ci = 0; ci < 4; ++ci) {
      if (ci >= nct) continue;
      #pragma unroll
      for (int bi = 0; bi < 2; ++bi) {
        if (bi >= nbt) continue;
        f32x4 a = z;
        #pragma unroll
        for (int kh = 0; kh < 2; ++kh)
          mfma3(a, ph[1][ci][kh], pl[1][ci][kh], bfh[1][bi][kh], bfl[1][bi][kh]);
        const f32x4 pr = a0[ci][bi] * a;
        if (rootout)
          *rootout = pr;
        else
          node_write(outSlot, (bt0 + bi) * 16 + ln, (ct0 + ci) * 4 + kq, pr);
      }
    }
  };

  // L0: 16 pairs (leaves), 2 per wave -> slots 0..15
  do_pair(0, w, -1, -1, w, 0, 2, 0, 4, true, nullptr);
  do_pair(0, w + 8, -1, -1, w + 8, 0, 2, 0, 4, true, nullptr);
  __syncthreads();
  // L1: 8 pairs, 1/wave: slots (2w, 2w+1) -> 2w
  do_pair(32, w, 2 * w, 2 * w + 1, 2 * w, 0, 2, 0, 4, false, nullptr);
  __syncthreads();
  // L2: 4 pairs x 2 bi-waves: slots (4j, 4j+2) -> 4j
  {
    const int j = w >> 1, bi = w & 1;
    do_pair(48, j, 4 * j, 4 * j + 2, 4 * j, bi, 1, 0, 4, false, nullptr);
  }
  __syncthreads();
  // L3: 2 pairs x (bi, ct-half): slots (8j, 8j+4) -> 8j+1
  {
    const int j = w >> 2, bi = w & 1, ch = (w >> 1) & 1;
    do_pair(56, j, 8 * j, 8 * j + 4, 8 * j + 1, bi, 1, ch * 2, 2, false,
            nullptr);
  }
  __syncthreads();
  // L4 root: slots (1, 9); 8 waves = (bi, ct); fused dot with pi
  {
    f32x4 pr = z;
    do_pair(60, 0, 1, 9, -1, w & 1, 1, w >> 1, 1, false, &pr);
    const f32x4 piv =
        *(const f32x4*)&ws[OFF_PI + (size_t)m * 64 + (w >> 1) * 16 + kq * 4];
    float v = pr.x * piv.x + pr.y * piv.y + pr.z * piv.z + pr.w * piv.w;
    v += __shfl_xor(v, 16, 64);
    v += __shfl_xor(v, 32, 64);
    if (lane < 16) psum[w & 1][w >> 1][lane] = v;
  }
  __syncthreads();
  if (tid < 32) {
    const int bi = tid >> 4, bb = tid & 15;
    out[(size_t)(btile * 32 + tid) * 8 + m] =
        psum[bi][0][bb] + psum[bi][1][bb] + psum[bi][2][bb] + psum[bi][3][bb];
  }
}

extern "C" void kernel_launch(void* const* d_in, const int* in_sizes, int n_in,
                              void* d_out, int out_size, void* d_ws, size_t ws_size,
                              hipStream_t stream) {
  const float* leaves  = (const float*)d_in[0];  // (B, 32, 64)
  const float* R_inv   = (const float*)d_in[1];  // (8, 2016)
  const float* pi_inv  = (const float*)d_in[2];  // (8, 63)
  const float* lengths = (const float*)d_in[3];  // (62,)
  float* out = (float*)d_out;                    // (B, 8)
  float* ws  = (float*)d_ws;

  u16* PBH = (u16*)(ws + OFF_PBH);
  u16* PBL = (u16*)(ws + OFF_PBL);

  hipLaunchKernelGGL(k_pcomb, dim3(256), dim3(512), 0, stream, R_inv, pi_inv,
                     lengths, ws, PBH, PBL);
  hipLaunchKernelGGL(k_tree, dim3(256), dim3(512), 0, stream, leaves, PBH, PBL,
                     ws, out);
}